// Round 6
// baseline (3105.787 us; speedup 1.0000x reference)
//
#include <hip/hip_runtime.h>
#include <hip/hip_bf16.h>

// ---------------------------------------------------------------------------
// BiLSTM-CRF on MI355X, round 10.
//  r9 post-mortem: asm-pinned poll regressed 18% vs r5's compiler codegen
//  (vmcnt(0) drains prev-step store ack; shfl epilogue duplicates elementwise
//  across lane halves). Topology, not codegen, is the lever.
//  Round-10 (k3): 32 blocks/dir x 16 cells (was 64 x 8).
//   - all-to-all poll traffic halves: 2MB/round/dir, half the polling waves
//     -> less fabric contention -> shorter detect latency.
//   - 16 cells/block => each gate = one full 16-row MFMA tile => all 4 gates
//     of a cell live in the SAME lane: epilogue has ZERO cross-lane ops
//     (no LDS, no barrier, no shfl), no duplicated elementwise; all 64
//     lanes store one 8B word (two contiguous 256B runs per wave).
//   - poll loop is r5-verbatim (batched __hip_atomic_load + single __all):
//     the best-measured poll codegen (3.5us/step at 2x today's contention).
//   - W_hh residency doubles: Bf[64] frags (256 regs, unified VGPR/AGPR file,
//     1 block/CU, launch_bounds(256,1)).
//  r5: sentinel protocol (0xFFFF bf16 unreachable for h in (-1,1)).
//  r4: frag-order H layout; k4 consumes unchanged (mapping re-verified).
// ---------------------------------------------------------------------------

typedef short short8  __attribute__((ext_vector_type(8)));
typedef short short4v __attribute__((ext_vector_type(4)));
typedef float floatx4 __attribute__((ext_vector_type(4)));

#define OFF_XQ    0ULL               // [2*64][512] blocks of 2048 bf16  268,435,456 B
#define OFF_H     268435456ULL       // [2][512] frag-order blocks 64KB   67,108,864 B
#define OFF_EMB   335544320ULL       // [32768][512] bf16                 33,554,432 B
#define OFF_WIH   369098752ULL       // [2][2048][512] bf16                4,194,304 B
#define OFF_FCW   373293056ULL       // [48][1024] bf16                       98,304 B
#define OFF_BIAS  373391360ULL       // [2][2048] f32                         16,384 B
#define OFF_EM    373538816ULL       // [32768][48] f32                    6,291,456 B
#define OFF_NUM   379830272ULL       // [64] f32
#define OFF_LOGZ  379830528ULL       // [64] f32
#define WS_NEED   379830784ULL

__device__ __forceinline__ unsigned short f2bf(float f) {
  __hip_bfloat16 h = __float2bfloat16(f);
  unsigned short u; __builtin_memcpy(&u, &h, 2); return u;
}
__device__ __forceinline__ float bf2f(unsigned short u) {
  __hip_bfloat16 h; __builtin_memcpy(&h, &u, 2); return __bfloat162float(h);
}
__device__ __forceinline__ float sigm(float x) { return 1.0f / (1.0f + __expf(-x)); }
__device__ __forceinline__ float tanh_f(float x) {
  x = fmaxf(fminf(x, 15.0f), -15.0f);
  float e = __expf(2.0f * x);
  return (e - 1.0f) / (e + 1.0f);
}
// bijective time->block scramble (keeps H-slot addresses spread)
__device__ __forceinline__ int permt(int t) { return (t * 167) & 511; }

// ---------------- k_init: fill Hall with sentinel 0xFFFFFFFF ----------------
__global__ void k_init(uint4* __restrict__ H) {
  size_t i = (size_t)blockIdx.x * 256 + threadIdx.x;   // 16384*256 uint4 = 64 MB
  H[i] = (uint4){0xFFFFFFFFu, 0xFFFFFFFFu, 0xFFFFFFFFu, 0xFFFFFFFFu};
}

// ---------------- k0: conversions ----------------
__global__ void k0_conv(const float* __restrict__ wf, const float* __restrict__ wb,
                        const float* __restrict__ fcw,
                        const float* __restrict__ bihf, const float* __restrict__ bhhf,
                        const float* __restrict__ bihb, const float* __restrict__ bhhb,
                        unsigned short* __restrict__ wih_bf,
                        unsigned short* __restrict__ fcw_bf,
                        float* __restrict__ bias) {
  int i = blockIdx.x * 256 + threadIdx.x;
  if (i < 1048576) { wih_bf[i] = f2bf(wf[i]); return; }
  int j = i - 1048576;
  if (j < 1048576) { wih_bf[1048576 + j] = f2bf(wb[j]); return; }
  j -= 1048576;
  if (j < 49152) { fcw_bf[j] = f2bf(fcw[j]); return; }
  j -= 49152;
  if (j < 2048) { bias[j] = bihf[j] + bhhf[j]; return; }
  j -= 2048;
  if (j < 2048) { bias[2048 + j] = bihb[j] + bhhb[j]; return; }
}

// ---------------- k1: embedding gather -> bf16 ----------------
__global__ void k1_embed(const float* __restrict__ tab, const int* __restrict__ x,
                         unsigned short* __restrict__ emb_bf) {
  int tid = threadIdx.x;
#pragma unroll
  for (int r = 0; r < 4; ++r) {
    int m = blockIdx.x * 4 + r;          // m = t*64 + b
    int b = m & 63, t = m >> 6;
    int tok = x[b * 512 + t];
    const float2* src = (const float2*)(tab + (size_t)tok * 512);
    float2 v = src[tid];
    unsigned int pk = (unsigned int)f2bf(v.x) | ((unsigned int)f2bf(v.y) << 16);
    ((unsigned int*)(emb_bf + (size_t)m * 512))[tid] = pk;
  }
}

// ---------------- k2: input-projection GEMM -> xq layout ----------------
// xq block index (d*64+g)*512 + t, 2048 bf16 per block, inner: gate*512 + b*8 + ce
__global__ __launch_bounds__(256) void k2_xproj(
    const unsigned short* __restrict__ emb_bf, const unsigned short* __restrict__ wih_bf,
    const float* __restrict__ bias, unsigned short* __restrict__ xq) {
  const int mt = blockIdx.x * 128;
  const int nt = blockIdx.y * 128;
  const int d  = blockIdx.z;
  const unsigned short* W = wih_bf + (size_t)d * 2048 * 512;
  __shared__ short Bs[32768];                     // 64 KB (also epilogue scratch)
  const int tid = threadIdx.x, l = tid & 63, wv = tid >> 6;
  const int mh = wv & 1, nh = wv >> 1;
  floatx4 acc[4][4];
#pragma unroll
  for (int a = 0; a < 4; ++a)
#pragma unroll
    for (int b = 0; b < 4; ++b) acc[a][b] = (floatx4){0.f, 0.f, 0.f, 0.f};
  const unsigned short* Abase = emb_bf + (size_t)(mt + mh * 64) * 512;

  for (int kc = 0; kc < 2; ++kc) {
    __syncthreads();
#pragma unroll
    for (int i = 0; i < 16; ++i) {                // stage 64 B-fragments
      int f = i * 4 + wv;
      int nb2 = f & 7, ks = f >> 3;
      int n = nt + nb2 * 16 + (l & 15);
      int k = kc * 256 + ks * 32 + (l >> 4) * 8;
      short8 v = *(const short8*)(W + (size_t)n * 512 + k);
      *(short8*)(Bs + (f * 64 + l) * 8) = v;
    }
    __syncthreads();
#pragma unroll
    for (int ks = 0; ks < 8; ++ks) {
      int k0 = kc * 256 + ks * 32 + (l >> 4) * 8;
      short8 a[4];
#pragma unroll
      for (int mf = 0; mf < 4; ++mf)
        a[mf] = *(const short8*)(Abase + (size_t)(mf * 16 + (l & 15)) * 512 + k0);
#pragma unroll
      for (int nf = 0; nf < 4; ++nf) {
        short8 bfr = *(const short8*)(Bs + ((ks * 8 + nh * 4 + nf) * 64 + l) * 8);
#pragma unroll
        for (int mf = 0; mf < 4; ++mf)
          acc[mf][nf] = __builtin_amdgcn_mfma_f32_16x16x32_bf16(a[mf], bfr, acc[mf][nf], 0, 0, 0);
      }
    }
  }
  // ---- epilogue: LDS transpose into xq block layout ----
  __syncthreads();
#pragma unroll
  for (int nf = 0; nf < 4; ++nf) {
    int nl = nh * 64 + nf * 16 + (l & 15);
    float bs = bias[d * 2048 + nt + nl];
#pragma unroll
    for (int mf = 0; mf < 4; ++mf)
#pragma unroll
      for (int r = 0; r < 4; ++r) {
        int ml = mh * 64 + mf * 16 + (l >> 4) * 4 + r;
        Bs[ml * 136 + nl] = (short)f2bf(acc[mf][nf][r] + bs);  // stride 136: 16B-aligned rows
      }
  }
  __syncthreads();
  const int chunk = tid >> 3, sub = tid & 7;      // 32 chunks x 8 threads
  const int g_l = chunk & 15, t_l = chunk >> 4;
  const int gate = nt >> 9, g0 = (nt & 511) >> 3;
  size_t base = (((size_t)(d * 64 + g0 + g_l) * 512) + (size_t)(blockIdx.x * 2 + t_l)) * 2048
                + (size_t)gate * 512 + (size_t)sub * 64;
#pragma unroll
  for (int i = 0; i < 8; ++i) {                   // b = sub*8+i, pos = b*8+ce
    short8 v = *(const short8*)(Bs + (t_l * 64 + sub * 8 + i) * 136 + g_l * 8);
    *(short8*)(xq + base + i * 8) = v;
  }
}

// ---------------- k3: persistent BiLSTM, 32 blocks/dir x 16 cells ----------------
__global__ __launch_bounds__(256, 1) void k3_lstm(
    const float* __restrict__ whh_f, const float* __restrict__ whh_b,
    const unsigned short* __restrict__ xq, unsigned short* __restrict__ Hall) {
  const int wgid = blockIdx.x;
  const int d = wgid >> 5, g = wgid & 31;        // 32 blocks/dir, 16 cells each
  const int tid = threadIdx.x, l = tid & 63, wv = tid >> 6;
  const float* whh = d ? whh_b : whh_f;

  // W_hh: cells [g*16, g*16+16) x 4 gates as 64 A-operand fragments.
  // Bf[ks*4+gate]: row (l&15) = cell within gate, k = ks*32 + (l>>4)*8.
  short8 Bf[64];
#pragma unroll
  for (int ks = 0; ks < 16; ++ks) {
#pragma unroll
    for (int gate = 0; gate < 4; ++gate) {
      int row = gate * 512 + g * 16 + (l & 15);
      int k0 = ks * 32 + (l >> 4) * 8;
      const float* src = whh + (size_t)row * 512 + k0;
      short8 v;
#pragma unroll
      for (int j = 0; j < 8; ++j) v[j] = (short)f2bf(src[j]);
      Bf[ks * 4 + gate] = v;
    }
  }

  const int q  = l >> 4;            // lane quarter: owns cells g*16 + q*4 .. +4
  const int bl = l & 15;            // batch low bits
  const int b  = wv * 16 + bl;      // this lane's batch
  float cst[4] = {0.f, 0.f, 0.f, 0.f};

  const unsigned long long* Hb =
      (const unsigned long long*)((const unsigned int*)Hall + (size_t)d * 8388608);
  unsigned long long* Hwb =
      (unsigned long long*)((unsigned int*)Hall + (size_t)d * 8388608);
  // xq old-block granularity is 8 cells: this lane's cells live in old block
  // go = 2g + (q>>1), at inner cell offset (q&1)*4.
  const unsigned short* xqd = xq + ((size_t)(d * 64 + 2 * g + (q >> 1)) * 512) * 2048;

  // producer 8B slot: cell-quad m = g*4 + q  ->  (ks=m>>3, kq=(m>>1)&3, j=m&1)
  // ULL idx within (d,t) frag block = wv*2048 + ks*128 + kq*32 + 2*bl + j
  const int m_quad = g * 4 + q;
  const size_t st8 = (size_t)wv * 2048 + (size_t)(m_quad >> 3) * 128
                     + (size_t)((m_quad >> 1) & 3) * 32 + 2 * bl + (m_quad & 1);

  for (int s = 0; s < 512; ++s) {
    const int t = d ? (511 - s) : s;

    // prefetch xq: per gate one 8B word = this lane's 4 cells of batch b
    const unsigned long long* xb = (const unsigned long long*)(xqd + (size_t)t * 2048);
    unsigned long long xu[4];
#pragma unroll
    for (int gate = 0; gate < 4; ++gate) xu[gate] = xb[gate * 128 + b * 2 + (q & 1)];

    floatx4 accA[4], accB[4];
#pragma unroll
    for (int gate = 0; gate < 4; ++gate) {
      accA[gate] = (floatx4){0.f, 0.f, 0.f, 0.f};
      accB[gate] = (floatx4){0.f, 0.f, 0.f, 0.f};
    }
    if (s > 0) {
      const int tp = d ? (t + 1) : (t - 1);
      // r5-verbatim batched poll: load full 16KB wave chunk, single __all gate.
      const unsigned long long* Hu = Hb + (size_t)permt(tp) * 8192 + (size_t)wv * 2048;
      unsigned long long u[32];
      for (;;) {
#pragma unroll
        for (int ks = 0; ks < 16; ++ks) {
          u[2 * ks]     = __hip_atomic_load(Hu + (size_t)ks * 128 + 2 * l,
                                            __ATOMIC_RELAXED, __HIP_MEMORY_SCOPE_AGENT);
          u[2 * ks + 1] = __hip_atomic_load(Hu + (size_t)ks * 128 + 2 * l + 1,
                                            __ATOMIC_RELAXED, __HIP_MEMORY_SCOPE_AGENT);
        }
        bool ok = true;
#pragma unroll
        for (int i = 0; i < 32; ++i) {
          ok &= ((unsigned int)u[i] != 0xFFFFFFFFu);
          ok &= ((unsigned int)(u[i] >> 32) != 0xFFFFFFFFu);
        }
        if (__all((int)ok)) break;
        __builtin_amdgcn_s_sleep(1);
      }
      // 8 independent MFMA chains (4 gates x 2 halves), swapped operands:
      // D[cell-of-gate][batch]; col=lane&15=batch, rows=(l>>4)*4+r.
#pragma unroll
      for (int ks = 0; ks < 16; ++ks) {
        short8 af;
        __builtin_memcpy(&af, &u[2 * ks], 8);
        __builtin_memcpy((char*)&af + 8, &u[2 * ks + 1], 8);
        if (ks < 8) {
#pragma unroll
          for (int gate = 0; gate < 4; ++gate)
            accA[gate] = __builtin_amdgcn_mfma_f32_16x16x32_bf16(Bf[ks * 4 + gate], af,
                                                                 accA[gate], 0, 0, 0);
        } else {
#pragma unroll
          for (int gate = 0; gate < 4; ++gate)
            accB[gate] = __builtin_amdgcn_mfma_f32_16x16x32_bf16(Bf[ks * 4 + gate], af,
                                                                 accB[gate], 0, 0, 0);
        }
      }
    }

    // ---- elementwise: all 4 gates of each cell live in THIS lane ----
    float h4[4];
#pragma unroll
    for (int r = 0; r < 4; ++r) {
      float gi = accA[0][r] + accB[0][r] + bf2f((unsigned short)(xu[0] >> (16 * r)));
      float gf = accA[1][r] + accB[1][r] + bf2f((unsigned short)(xu[1] >> (16 * r)));
      float gg = accA[2][r] + accB[2][r] + bf2f((unsigned short)(xu[2] >> (16 * r)));
      float go = accA[3][r] + accB[3][r] + bf2f((unsigned short)(xu[3] >> (16 * r)));
      float c = sigm(gf) * cst[r] + sigm(gi) * tanh_f(gg);
      cst[r] = c;
      h4[r] = sigm(go) * tanh_f(c);
    }
    // every lane stores its 4 cells as one 8B word; wave = 2x 256B contiguous runs
    unsigned int d0 = (unsigned int)f2bf(h4[0]) | ((unsigned int)f2bf(h4[1]) << 16);
    unsigned int d1 = (unsigned int)f2bf(h4[2]) | ((unsigned int)f2bf(h4[3]) << 16);
    unsigned long long hp = (unsigned long long)d0 | ((unsigned long long)d1 << 32);
    __hip_atomic_store(Hwb + (size_t)permt(t) * 8192 + st8, hp,
                       __ATOMIC_RELAXED, __HIP_MEMORY_SCOPE_AGENT);
  }
}

// ---------------- k4: emissions GEMM (frag-order H) ----------------
__global__ __launch_bounds__(256) void k4_emis(
    const unsigned short* __restrict__ Hall, const unsigned short* __restrict__ fcw_bf,
    const float* __restrict__ fcb, float* __restrict__ em) {
  __shared__ short Fs[48 * 520];
  const int tid = threadIdx.x, l = tid & 63, wv = tid >> 6;
  const int t = blockIdx.x;                      // M-tile 64 = one timestep
  floatx4 acc[3];
  acc[0] = acc[1] = acc[2] = (floatx4){0.f, 0.f, 0.f, 0.f};
  for (int half = 0; half < 2; ++half) {
    __syncthreads();
#pragma unroll
    for (int i = 0; i < 24; ++i) {
      int e4 = (tid + i * 256) * 4;
      int n = e4 >> 9, k = e4 & 511;
      *(short4v*)(Fs + n * 520 + k) =
          *(const short4v*)(fcw_bf + (size_t)n * 1024 + half * 512 + k);
    }
    __syncthreads();
    const unsigned short* Hsrc = Hall + (size_t)half * 16777216 + (size_t)permt(t) * 32768
                                 + (size_t)wv * 8192 + l * 8;
#pragma unroll
    for (int ks = 0; ks < 16; ++ks) {
      short8 a = *(const short8*)(Hsrc + ks * 512);
#pragma unroll
      for (int nf = 0; nf < 3; ++nf) {
        short8 bfr = *(const short8*)(Fs + (nf * 16 + (l & 15)) * 520 + ks * 32 + (l >> 4) * 8);
        acc[nf] = __builtin_amdgcn_mfma_f32_16x16x32_bf16(a, bfr, acc[nf], 0, 0, 0);
      }
    }
  }
#pragma unroll
  for (int nf = 0; nf < 3; ++nf) {
    int n = nf * 16 + (l & 15);
    float bv = fcb[n];
#pragma unroll
    for (int r = 0; r < 4; ++r) {
      int m = wv * 16 + (l >> 4) * 4 + r;        // batch
      em[((size_t)t * 64 + m) * 48 + n] = acc[nf][r] + bv;
    }
  }
}

// ---------------- k5: CRF numerator ----------------
__global__ void k5_num(const float* __restrict__ em, const int* __restrict__ tags,
                       const float* __restrict__ start, const float* __restrict__ endt,
                       const float* __restrict__ trans, float* __restrict__ num) {
  const int b = blockIdx.x, tid = threadIdx.x;
  float s = 0.f;
  for (int t = 1 + tid; t < 512; t += 256) {
    int tg = tags[b * 512 + t], tp = tags[b * 512 + t - 1];
    s += em[(size_t)(t * 64 + b) * 48 + tg] + trans[tp * 48 + tg];
  }
  if (tid == 0) {
    int t0 = tags[b * 512];
    s += start[t0] + em[(size_t)b * 48 + t0] + endt[tags[b * 512 + 511]];
  }
  __shared__ float red[256];
  red[tid] = s;
  __syncthreads();
  for (int o = 128; o > 0; o >>= 1) {
    if (tid < o) red[tid] += red[tid + o];
    __syncthreads();
  }
  if (tid == 0) num[b] = red[0];
}

// ---------------- k6: CRF forward recursion (single wave, no barriers) ----------------
__global__ void k6_crf(const float* __restrict__ em, const float* __restrict__ trans,
                       const float* __restrict__ start, const float* __restrict__ endt,
                       float* __restrict__ logz) {
  const int b = blockIdx.x;
  const int j = threadIdx.x;   // 64 threads = ONE wave; lanes 48..63 inactive
  const bool act = j < 48;
  float Ecol[48];
#pragma unroll
  for (int i = 0; i < 48; ++i) Ecol[i] = act ? __expf(trans[i * 48 + j]) : 0.f;
  __shared__ float p[48];
  float alpha = act ? (start[j] + em[(size_t)b * 48 + j]) : -1e30f;
  for (int t = 1; t < 512; ++t) {
    float e_t = act ? em[(size_t)(t * 64 + b) * 48 + j] : 0.f;
    float m = alpha;
#pragma unroll
    for (int off = 32; off > 0; off >>= 1) m = fmaxf(m, __shfl_xor(m, off));
    if (act) p[j] = __expf(alpha - m);
    float ssum = 0.f;                       // single wave: LDS ops in-order, no barrier
#pragma unroll
    for (int i = 0; i < 48; ++i) ssum += p[i] * Ecol[i];
    alpha = act ? (m + __logf(ssum) + e_t) : -1e30f;
  }
  float v = act ? (alpha + endt[j]) : -1e30f;
  float m2 = v;
#pragma unroll
  for (int off = 32; off > 0; off >>= 1) m2 = fmaxf(m2, __shfl_xor(m2, off));
  float sz = act ? __expf(v - m2) : 0.f;
#pragma unroll
  for (int off = 32; off > 0; off >>= 1) sz += __shfl_xor(sz, off);
  if (j == 0) logz[b] = m2 + __logf(sz);
}

// ---------------- k7: final scalar ----------------
__global__ void k7_final(const float* __restrict__ num, const float* __restrict__ logz,
                         float* __restrict__ out) {
  int l = threadIdx.x;
  float v = num[l] - logz[l];
#pragma unroll
  for (int off = 32; off > 0; off >>= 1) v += __shfl_xor(v, off);
  if (l == 0) out[0] = -v * (1.0f / 64.0f);
}

// ---------------------------------------------------------------------------
extern "C" void kernel_launch(void* const* d_in, const int* in_sizes, int n_in,
                              void* d_out, int out_size, void* d_ws, size_t ws_size,
                              hipStream_t stream) {
  (void)in_sizes; (void)n_in; (void)out_size;
  if (ws_size < WS_NEED) return;

  const float* embedding = (const float*)d_in[0];
  const float* w_ih_f = (const float*)d_in[1];
  const float* w_hh_f = (const float*)d_in[2];
  const float* b_ih_f = (const float*)d_in[3];
  const float* b_hh_f = (const float*)d_in[4];
  const float* w_ih_b = (const float*)d_in[5];
  const float* w_hh_b = (const float*)d_in[6];
  const float* b_ih_b = (const float*)d_in[7];
  const float* b_hh_b = (const float*)d_in[8];
  const float* fc_w = (const float*)d_in[9];
  const float* fc_b = (const float*)d_in[10];
  const float* start_trans = (const float*)d_in[11];
  const float* end_trans = (const float*)d_in[12];
  const float* trans = (const float*)d_in[13];
  const int* x = (const int*)d_in[14];
  const int* tags = (const int*)d_in[15];

  char* ws = (char*)d_ws;
  unsigned short* xq     = (unsigned short*)(ws + OFF_XQ);
  unsigned short* Hall   = (unsigned short*)(ws + OFF_H);
  unsigned short* emb_bf = (unsigned short*)(ws + OFF_EMB);
  unsigned short* wih_bf = (unsigned short*)(ws + OFF_WIH);
  unsigned short* fcw_bf = (unsigned short*)(ws + OFF_FCW);
  float* bias  = (float*)(ws + OFF_BIAS);
  float* em    = (float*)(ws + OFF_EM);
  float* num   = (float*)(ws + OFF_NUM);
  float* logz  = (float*)(ws + OFF_LOGZ);

  k_init<<<16384, 256, 0, stream>>>((uint4*)Hall);
  k0_conv<<<8400, 256, 0, stream>>>(w_ih_f, w_ih_b, fc_w, b_ih_f, b_hh_f, b_ih_b, b_hh_b,
                                    wih_bf, fcw_bf, bias);
  k1_embed<<<8192, 256, 0, stream>>>(embedding, x, emb_bf);
  k2_xproj<<<dim3(256, 16, 2), 256, 0, stream>>>(emb_bf, wih_bf, bias, xq);
  k3_lstm<<<64, 256, 0, stream>>>(w_hh_f, w_hh_b, xq, Hall);
  k4_emis<<<512, 256, 0, stream>>>(Hall, fcw_bf, fc_b, em);
  k5_num<<<64, 256, 0, stream>>>(em, tags, start_trans, end_trans, trans, num);
  k6_crf<<<64, 64, 0, stream>>>(em, trans, start_trans, end_trans, logz);
  k7_final<<<1, 64, 0, stream>>>(num, logz, (float*)d_out);
}

// Round 7
// 2872.527 us; speedup vs baseline: 1.0812x; 1.0812x over previous
//
#include <hip/hip_runtime.h>
#include <hip/hip_bf16.h>

// ---------------------------------------------------------------------------
// BiLSTM-CRF on MI355X, round 11.
//  r10 post-mortem: Bf[64]=256 regs + u[32] blew the register file (VGPR=216
//  reported -> spill/remat, FETCH +100MB, 4.3us/step). Residency bets must be
//  checked against the register budget.
//  Round-11 (k3) = minimal diff from r5 (the measured-best 3.5us/step):
//   - r5 topology: 64 blocks/dir x 8 cells. r5 poll-consume codegen shape
//     verbatim (batched __hip_atomic_load x32, ONE __all gate, s_sleep).
//   - swapped-operand MFMA with cell-pair row permutation: frag row
//     nl = cA*4 + gate; tile A = even cells (2cA), tile B = odd (2cA+1).
//     Lane (q,bl) = all 4 gates of cells 2q,2q+1, batch bl -> epilogue has
//     ZERO cross-lane ops (r5's LDS transpose + barrier deleted, r9's shfl
//     chain deleted, no duplicated elementwise).
//   - cells 2q,2q+1 adjacent in frag layout -> one aligned dword store per
//     lane, 256B contiguous per wave (same full-line store shape as r4/r5;
//     mapping re-derived against k4's read formula).
//   - register budget: Bf[32]=128 + u[32]=64 + 4 acc chains=16 + misc ~= 240.
//  r5: sentinel protocol (0xFFFF bf16 unreachable for h in (-1,1)).
//  r4: frag-order H layout; k4 consumes unchanged.
// ---------------------------------------------------------------------------

typedef short short8  __attribute__((ext_vector_type(8)));
typedef short short4v __attribute__((ext_vector_type(4)));
typedef float floatx4 __attribute__((ext_vector_type(4)));

#define OFF_XQ    0ULL               // [2*64][512] blocks of 2048 bf16  268,435,456 B
#define OFF_H     268435456ULL       // [2][512] frag-order blocks 64KB   67,108,864 B
#define OFF_EMB   335544320ULL       // [32768][512] bf16                 33,554,432 B
#define OFF_WIH   369098752ULL       // [2][2048][512] bf16                4,194,304 B
#define OFF_FCW   373293056ULL       // [48][1024] bf16                       98,304 B
#define OFF_BIAS  373391360ULL       // [2][2048] f32                         16,384 B
#define OFF_EM    373538816ULL       // [32768][48] f32                    6,291,456 B
#define OFF_NUM   379830272ULL       // [64] f32
#define OFF_LOGZ  379830528ULL       // [64] f32
#define WS_NEED   379830784ULL

__device__ __forceinline__ unsigned short f2bf(float f) {
  __hip_bfloat16 h = __float2bfloat16(f);
  unsigned short u; __builtin_memcpy(&u, &h, 2); return u;
}
__device__ __forceinline__ float bf2f(unsigned short u) {
  __hip_bfloat16 h; __builtin_memcpy(&h, &u, 2); return __bfloat162float(h);
}
__device__ __forceinline__ float sigm(float x) { return 1.0f / (1.0f + __expf(-x)); }
__device__ __forceinline__ float tanh_f(float x) {
  x = fmaxf(fminf(x, 15.0f), -15.0f);
  float e = __expf(2.0f * x);
  return (e - 1.0f) / (e + 1.0f);
}
// bijective time->block scramble (keeps H-slot addresses spread)
__device__ __forceinline__ int permt(int t) { return (t * 167) & 511; }

// ---------------- k_init: fill Hall with sentinel 0xFFFFFFFF ----------------
__global__ void k_init(uint4* __restrict__ H) {
  size_t i = (size_t)blockIdx.x * 256 + threadIdx.x;   // 16384*256 uint4 = 64 MB
  H[i] = (uint4){0xFFFFFFFFu, 0xFFFFFFFFu, 0xFFFFFFFFu, 0xFFFFFFFFu};
}

// ---------------- k0: conversions ----------------
__global__ void k0_conv(const float* __restrict__ wf, const float* __restrict__ wb,
                        const float* __restrict__ fcw,
                        const float* __restrict__ bihf, const float* __restrict__ bhhf,
                        const float* __restrict__ bihb, const float* __restrict__ bhhb,
                        unsigned short* __restrict__ wih_bf,
                        unsigned short* __restrict__ fcw_bf,
                        float* __restrict__ bias) {
  int i = blockIdx.x * 256 + threadIdx.x;
  if (i < 1048576) { wih_bf[i] = f2bf(wf[i]); return; }
  int j = i - 1048576;
  if (j < 1048576) { wih_bf[1048576 + j] = f2bf(wb[j]); return; }
  j -= 1048576;
  if (j < 49152) { fcw_bf[j] = f2bf(fcw[j]); return; }
  j -= 49152;
  if (j < 2048) { bias[j] = bihf[j] + bhhf[j]; return; }
  j -= 2048;
  if (j < 2048) { bias[2048 + j] = bihb[j] + bhhb[j]; return; }
}

// ---------------- k1: embedding gather -> bf16 ----------------
__global__ void k1_embed(const float* __restrict__ tab, const int* __restrict__ x,
                         unsigned short* __restrict__ emb_bf) {
  int tid = threadIdx.x;
#pragma unroll
  for (int r = 0; r < 4; ++r) {
    int m = blockIdx.x * 4 + r;          // m = t*64 + b
    int b = m & 63, t = m >> 6;
    int tok = x[b * 512 + t];
    const float2* src = (const float2*)(tab + (size_t)tok * 512);
    float2 v = src[tid];
    unsigned int pk = (unsigned int)f2bf(v.x) | ((unsigned int)f2bf(v.y) << 16);
    ((unsigned int*)(emb_bf + (size_t)m * 512))[tid] = pk;
  }
}

// ---------------- k2: input-projection GEMM -> xq layout ----------------
// xq block index (d*64+g)*512 + t, 2048 bf16 per block, inner: gate*512 + b*8 + ce
__global__ __launch_bounds__(256) void k2_xproj(
    const unsigned short* __restrict__ emb_bf, const unsigned short* __restrict__ wih_bf,
    const float* __restrict__ bias, unsigned short* __restrict__ xq) {
  const int mt = blockIdx.x * 128;
  const int nt = blockIdx.y * 128;
  const int d  = blockIdx.z;
  const unsigned short* W = wih_bf + (size_t)d * 2048 * 512;
  __shared__ short Bs[32768];                     // 64 KB (also epilogue scratch)
  const int tid = threadIdx.x, l = tid & 63, wv = tid >> 6;
  const int mh = wv & 1, nh = wv >> 1;
  floatx4 acc[4][4];
#pragma unroll
  for (int a = 0; a < 4; ++a)
#pragma unroll
    for (int b = 0; b < 4; ++b) acc[a][b] = (floatx4){0.f, 0.f, 0.f, 0.f};
  const unsigned short* Abase = emb_bf + (size_t)(mt + mh * 64) * 512;

  for (int kc = 0; kc < 2; ++kc) {
    __syncthreads();
#pragma unroll
    for (int i = 0; i < 16; ++i) {                // stage 64 B-fragments
      int f = i * 4 + wv;
      int nb2 = f & 7, ks = f >> 3;
      int n = nt + nb2 * 16 + (l & 15);
      int k = kc * 256 + ks * 32 + (l >> 4) * 8;
      short8 v = *(const short8*)(W + (size_t)n * 512 + k);
      *(short8*)(Bs + (f * 64 + l) * 8) = v;
    }
    __syncthreads();
#pragma unroll
    for (int ks = 0; ks < 8; ++ks) {
      int k0 = kc * 256 + ks * 32 + (l >> 4) * 8;
      short8 a[4];
#pragma unroll
      for (int mf = 0; mf < 4; ++mf)
        a[mf] = *(const short8*)(Abase + (size_t)(mf * 16 + (l & 15)) * 512 + k0);
#pragma unroll
      for (int nf = 0; nf < 4; ++nf) {
        short8 bfr = *(const short8*)(Bs + ((ks * 8 + nh * 4 + nf) * 64 + l) * 8);
#pragma unroll
        for (int mf = 0; mf < 4; ++mf)
          acc[mf][nf] = __builtin_amdgcn_mfma_f32_16x16x32_bf16(a[mf], bfr, acc[mf][nf], 0, 0, 0);
      }
    }
  }
  // ---- epilogue: LDS transpose into xq block layout ----
  __syncthreads();
#pragma unroll
  for (int nf = 0; nf < 4; ++nf) {
    int nl = nh * 64 + nf * 16 + (l & 15);
    float bs = bias[d * 2048 + nt + nl];
#pragma unroll
    for (int mf = 0; mf < 4; ++mf)
#pragma unroll
      for (int r = 0; r < 4; ++r) {
        int ml = mh * 64 + mf * 16 + (l >> 4) * 4 + r;
        Bs[ml * 136 + nl] = (short)f2bf(acc[mf][nf][r] + bs);  // stride 136: 16B-aligned rows
      }
  }
  __syncthreads();
  const int chunk = tid >> 3, sub = tid & 7;      // 32 chunks x 8 threads
  const int g_l = chunk & 15, t_l = chunk >> 4;
  const int gate = nt >> 9, g0 = (nt & 511) >> 3;
  size_t base = (((size_t)(d * 64 + g0 + g_l) * 512) + (size_t)(blockIdx.x * 2 + t_l)) * 2048
                + (size_t)gate * 512 + (size_t)sub * 64;
#pragma unroll
  for (int i = 0; i < 8; ++i) {                   // b = sub*8+i, pos = b*8+ce
    short8 v = *(const short8*)(Bs + (t_l * 64 + sub * 8 + i) * 136 + g_l * 8);
    *(short8*)(xq + base + i * 8) = v;
  }
}

// ---------------- k3: persistent BiLSTM, lane-local gates, no LDS/barrier ----------------
__global__ __launch_bounds__(256, 1) void k3_lstm(
    const float* __restrict__ whh_f, const float* __restrict__ whh_b,
    const unsigned short* __restrict__ xq, unsigned short* __restrict__ Hall) {
  const int wgid = blockIdx.x;
  const int d = wgid >> 6, g = wgid & 63;
  const int tid = threadIdx.x, l = tid & 63, wv = tid >> 6;
  const float* whh = d ? whh_b : whh_f;

  // W_hh as MFMA A-operand fragments with cell-pair row permutation:
  // frag row nl = cA*4 + gate; tile T=0 -> cell 2cA, T=1 -> cell 2cA+1.
  // Bf[ks*2+T]; lane's k = ks*32 + (l>>4)*8.
  short8 Bf[32];
#pragma unroll
  for (int ks = 0; ks < 16; ++ks) {
#pragma unroll
    for (int T = 0; T < 2; ++T) {
      int nl = l & 15;
      int cA = nl >> 2, gate = nl & 3;
      int row = gate * 512 + g * 8 + 2 * cA + T;
      int k0 = ks * 32 + (l >> 4) * 8;
      const float* src = whh + (size_t)row * 512 + k0;
      short8 v;
#pragma unroll
      for (int j = 0; j < 8; ++j) v[j] = (short)f2bf(src[j]);
      Bf[ks * 2 + T] = v;
    }
  }

  const int q  = l >> 4;            // lane quarter: owns cells 2q, 2q+1
  const int bl = l & 15;            // batch low bits
  const int m  = wv * 16 + bl;      // this lane's batch
  float cst[2] = {0.f, 0.f};

  const unsigned long long* Hb =
      (const unsigned long long*)((const unsigned int*)Hall + (size_t)d * 8388608);
  unsigned int* Hw = (unsigned int*)Hall + (size_t)d * 8388608;
  const unsigned short* xqd = xq + ((size_t)(d * 64 + g) * 512) * 2048;

  // producer dword slot within a (d,t) 16384-dword frag block:
  // dims k1=8g+2q (low short), k2=8g+2q+1 (high) of batch m ->
  // dw = wv*4096 + (g>>2)*256 + (g&3)*64 + bl*4 + q  (wave = 256B contiguous)
  const size_t st_dw = (size_t)wv * 4096 + (size_t)(g >> 2) * 256
                     + (size_t)(g & 3) * 64 + bl * 4 + q;

  for (int s = 0; s < 512; ++s) {
    const int t = d ? (511 - s) : s;

    // prefetch xq: one dword per gate = cells 2q,2q+1 of batch m
    const unsigned int* xb = (const unsigned int*)(xqd + (size_t)t * 2048);
    unsigned int xu[4];
#pragma unroll
    for (int gate = 0; gate < 4; ++gate) xu[gate] = xb[gate * 256 + m * 4 + q];

    floatx4 acc0  = (floatx4){0.f, 0.f, 0.f, 0.f};   // cell 2q,   gates i,f,g,o
    floatx4 acc1  = (floatx4){0.f, 0.f, 0.f, 0.f};   // cell 2q+1, gates i,f,g,o
    floatx4 acc0b = (floatx4){0.f, 0.f, 0.f, 0.f};
    floatx4 acc1b = (floatx4){0.f, 0.f, 0.f, 0.f};
    if (s > 0) {
      const int tp = d ? (t + 1) : (t - 1);
      // r5-verbatim batched poll: load full 16KB wave chunk, single __all gate.
      const unsigned long long* Hu = Hb + (size_t)permt(tp) * 8192 + (size_t)wv * 2048;
      unsigned long long u[32];
      for (;;) {
#pragma unroll
        for (int ks = 0; ks < 16; ++ks) {
          u[2 * ks]     = __hip_atomic_load(Hu + (size_t)ks * 128 + 2 * l,
                                            __ATOMIC_RELAXED, __HIP_MEMORY_SCOPE_AGENT);
          u[2 * ks + 1] = __hip_atomic_load(Hu + (size_t)ks * 128 + 2 * l + 1,
                                            __ATOMIC_RELAXED, __HIP_MEMORY_SCOPE_AGENT);
        }
        bool ok = true;
#pragma unroll
        for (int i = 0; i < 32; ++i) {
          ok &= ((unsigned int)u[i] != 0xFFFFFFFFu);
          ok &= ((unsigned int)(u[i] >> 32) != 0xFFFFFFFFu);
        }
        if (__all((int)ok)) break;
        __builtin_amdgcn_s_sleep(1);
      }
      // 4 independent 8-deep MFMA chains; swapped operands -> D[nl][batch]:
      // lane (q,bl) holds rows 4q..4q+3 = (cA=q, gates 0..3), col = batch bl.
#pragma unroll
      for (int ks = 0; ks < 8; ++ks) {
        short8 af0, af1;
        __builtin_memcpy(&af0, &u[2 * ks], 8);
        __builtin_memcpy((char*)&af0 + 8, &u[2 * ks + 1], 8);
        __builtin_memcpy(&af1, &u[2 * (ks + 8)], 8);
        __builtin_memcpy((char*)&af1 + 8, &u[2 * (ks + 8) + 1], 8);
        acc0  = __builtin_amdgcn_mfma_f32_16x16x32_bf16(Bf[ks * 2 + 0], af0, acc0, 0, 0, 0);
        acc1  = __builtin_amdgcn_mfma_f32_16x16x32_bf16(Bf[ks * 2 + 1], af0, acc1, 0, 0, 0);
        acc0b = __builtin_amdgcn_mfma_f32_16x16x32_bf16(Bf[(ks + 8) * 2 + 0], af1, acc0b, 0, 0, 0);
        acc1b = __builtin_amdgcn_mfma_f32_16x16x32_bf16(Bf[(ks + 8) * 2 + 1], af1, acc1b, 0, 0, 0);
      }
      acc0 += acc0b;
      acc1 += acc1b;
    }

    // ---- elementwise: all 4 gates of both cells live in THIS lane ----
    float h2[2];
#pragma unroll
    for (int T = 0; T < 2; ++T) {
      floatx4 a = T ? acc1 : acc0;
      float gi = a[0] + bf2f((unsigned short)(xu[0] >> (16 * T)));
      float gf = a[1] + bf2f((unsigned short)(xu[1] >> (16 * T)));
      float gg = a[2] + bf2f((unsigned short)(xu[2] >> (16 * T)));
      float go = a[3] + bf2f((unsigned short)(xu[3] >> (16 * T)));
      float c = sigm(gf) * cst[T] + sigm(gi) * tanh_f(gg);
      cst[T] = c;
      h2[T] = sigm(go) * tanh_f(c);
    }
    // one aligned dword per lane (cells 2q,2q+1 adjacent in frag layout);
    // wave = 256B contiguous run. Write-through agent store = the signal.
    unsigned int hp = (unsigned int)f2bf(h2[0]) | ((unsigned int)f2bf(h2[1]) << 16);
    __hip_atomic_store(&Hw[(size_t)permt(t) * 16384 + st_dw], hp,
                       __ATOMIC_RELAXED, __HIP_MEMORY_SCOPE_AGENT);
  }
}

// ---------------- k4: emissions GEMM (frag-order H) ----------------
__global__ __launch_bounds__(256) void k4_emis(
    const unsigned short* __restrict__ Hall, const unsigned short* __restrict__ fcw_bf,
    const float* __restrict__ fcb, float* __restrict__ em) {
  __shared__ short Fs[48 * 520];
  const int tid = threadIdx.x, l = tid & 63, wv = tid >> 6;
  const int t = blockIdx.x;                      // M-tile 64 = one timestep
  floatx4 acc[3];
  acc[0] = acc[1] = acc[2] = (floatx4){0.f, 0.f, 0.f, 0.f};
  for (int half = 0; half < 2; ++half) {
    __syncthreads();
#pragma unroll
    for (int i = 0; i < 24; ++i) {
      int e4 = (tid + i * 256) * 4;
      int n = e4 >> 9, k = e4 & 511;
      *(short4v*)(Fs + n * 520 + k) =
          *(const short4v*)(fcw_bf + (size_t)n * 1024 + half * 512 + k);
    }
    __syncthreads();
    const unsigned short* Hsrc = Hall + (size_t)half * 16777216 + (size_t)permt(t) * 32768
                                 + (size_t)wv * 8192 + l * 8;
#pragma unroll
    for (int ks = 0; ks < 16; ++ks) {
      short8 a = *(const short8*)(Hsrc + ks * 512);
#pragma unroll
      for (int nf = 0; nf < 3; ++nf) {
        short8 bfr = *(const short8*)(Fs + (nf * 16 + (l & 15)) * 520 + ks * 32 + (l >> 4) * 8);
        acc[nf] = __builtin_amdgcn_mfma_f32_16x16x32_bf16(a, bfr, acc[nf], 0, 0, 0);
      }
    }
  }
#pragma unroll
  for (int nf = 0; nf < 3; ++nf) {
    int n = nf * 16 + (l & 15);
    float bv = fcb[n];
#pragma unroll
    for (int r = 0; r < 4; ++r) {
      int m = wv * 16 + (l >> 4) * 4 + r;        // batch
      em[((size_t)t * 64 + m) * 48 + n] = acc[nf][r] + bv;
    }
  }
}

// ---------------- k5: CRF numerator ----------------
__global__ void k5_num(const float* __restrict__ em, const int* __restrict__ tags,
                       const float* __restrict__ start, const float* __restrict__ endt,
                       const float* __restrict__ trans, float* __restrict__ num) {
  const int b = blockIdx.x, tid = threadIdx.x;
  float s = 0.f;
  for (int t = 1 + tid; t < 512; t += 256) {
    int tg = tags[b * 512 + t], tp = tags[b * 512 + t - 1];
    s += em[(size_t)(t * 64 + b) * 48 + tg] + trans[tp * 48 + tg];
  }
  if (tid == 0) {
    int t0 = tags[b * 512];
    s += start[t0] + em[(size_t)b * 48 + t0] + endt[tags[b * 512 + 511]];
  }
  __shared__ float red[256];
  red[tid] = s;
  __syncthreads();
  for (int o = 128; o > 0; o >>= 1) {
    if (tid < o) red[tid] += red[tid + o];
    __syncthreads();
  }
  if (tid == 0) num[b] = red[0];
}

// ---------------- k6: CRF forward recursion (single wave, no barriers) ----------------
__global__ void k6_crf(const float* __restrict__ em, const float* __restrict__ trans,
                       const float* __restrict__ start, const float* __restrict__ endt,
                       float* __restrict__ logz) {
  const int b = blockIdx.x;
  const int j = threadIdx.x;   // 64 threads = ONE wave; lanes 48..63 inactive
  const bool act = j < 48;
  float Ecol[48];
#pragma unroll
  for (int i = 0; i < 48; ++i) Ecol[i] = act ? __expf(trans[i * 48 + j]) : 0.f;
  __shared__ float p[48];
  float alpha = act ? (start[j] + em[(size_t)b * 48 + j]) : -1e30f;
  for (int t = 1; t < 512; ++t) {
    float e_t = act ? em[(size_t)(t * 64 + b) * 48 + j] : 0.f;
    float m = alpha;
#pragma unroll
    for (int off = 32; off > 0; off >>= 1) m = fmaxf(m, __shfl_xor(m, off));
    if (act) p[j] = __expf(alpha - m);
    float ssum = 0.f;                       // single wave: LDS ops in-order, no barrier
#pragma unroll
    for (int i = 0; i < 48; ++i) ssum += p[i] * Ecol[i];
    alpha = act ? (m + __logf(ssum) + e_t) : -1e30f;
  }
  float v = act ? (alpha + endt[j]) : -1e30f;
  float m2 = v;
#pragma unroll
  for (int off = 32; off > 0; off >>= 1) m2 = fmaxf(m2, __shfl_xor(m2, off));
  float sz = act ? __expf(v - m2) : 0.f;
#pragma unroll
  for (int off = 32; off > 0; off >>= 1) sz += __shfl_xor(sz, off);
  if (j == 0) logz[b] = m2 + __logf(sz);
}

// ---------------- k7: final scalar ----------------
__global__ void k7_final(const float* __restrict__ num, const float* __restrict__ logz,
                         float* __restrict__ out) {
  int l = threadIdx.x;
  float v = num[l] - logz[l];
#pragma unroll
  for (int off = 32; off > 0; off >>= 1) v += __shfl_xor(v, off);
  if (l == 0) out[0] = -v * (1.0f / 64.0f);
}

// ---------------------------------------------------------------------------
extern "C" void kernel_launch(void* const* d_in, const int* in_sizes, int n_in,
                              void* d_out, int out_size, void* d_ws, size_t ws_size,
                              hipStream_t stream) {
  (void)in_sizes; (void)n_in; (void)out_size;
  if (ws_size < WS_NEED) return;

  const float* embedding = (const float*)d_in[0];
  const float* w_ih_f = (const float*)d_in[1];
  const float* w_hh_f = (const float*)d_in[2];
  const float* b_ih_f = (const float*)d_in[3];
  const float* b_hh_f = (const float*)d_in[4];
  const float* w_ih_b = (const float*)d_in[5];
  const float* w_hh_b = (const float*)d_in[6];
  const float* b_ih_b = (const float*)d_in[7];
  const float* b_hh_b = (const float*)d_in[8];
  const float* fc_w = (const float*)d_in[9];
  const float* fc_b = (const float*)d_in[10];
  const float* start_trans = (const float*)d_in[11];
  const float* end_trans = (const float*)d_in[12];
  const float* trans = (const float*)d_in[13];
  const int* x = (const int*)d_in[14];
  const int* tags = (const int*)d_in[15];

  char* ws = (char*)d_ws;
  unsigned short* xq     = (unsigned short*)(ws + OFF_XQ);
  unsigned short* Hall   = (unsigned short*)(ws + OFF_H);
  unsigned short* emb_bf = (unsigned short*)(ws + OFF_EMB);
  unsigned short* wih_bf = (unsigned short*)(ws + OFF_WIH);
  unsigned short* fcw_bf = (unsigned short*)(ws + OFF_FCW);
  float* bias  = (float*)(ws + OFF_BIAS);
  float* em    = (float*)(ws + OFF_EM);
  float* num   = (float*)(ws + OFF_NUM);
  float* logz  = (float*)(ws + OFF_LOGZ);

  k_init<<<16384, 256, 0, stream>>>((uint4*)Hall);
  k0_conv<<<8400, 256, 0, stream>>>(w_ih_f, w_ih_b, fc_w, b_ih_f, b_hh_f, b_ih_b, b_hh_b,
                                    wih_bf, fcw_bf, bias);
  k1_embed<<<8192, 256, 0, stream>>>(embedding, x, emb_bf);
  k2_xproj<<<dim3(256, 16, 2), 256, 0, stream>>>(emb_bf, wih_bf, bias, xq);
  k3_lstm<<<128, 256, 0, stream>>>(w_hh_f, w_hh_b, xq, Hall);
  k4_emis<<<512, 256, 0, stream>>>(Hall, fcw_bf, fc_b, em);
  k5_num<<<64, 256, 0, stream>>>(em, tags, start_trans, end_trans, trans, num);
  k6_crf<<<64, 64, 0, stream>>>(em, trans, start_trans, end_trans, logz);
  k7_final<<<1, 64, 0, stream>>>(num, logz, (float*)d_out);
}

// Round 8
// 2688.330 us; speedup vs baseline: 1.1553x; 1.0685x over previous
//
#include <hip/hip_runtime.h>
#include <hip/hip_bf16.h>

// ---------------------------------------------------------------------------
// BiLSTM-CRF on MI355X, round 12.
//  r11 post-mortem: barrier-free variants (r9/r10/r11) are ALL slower than r5
//  despite clean codegen (r11: VGPR=136, LDS=0, lane-local gates). Mechanism:
//  r5's __syncthreads forced a vmcnt(0) drain AFTER the h-store; without it a
//  wave issues its store then instantly floods the VMEM queue with 32 poll
//  loads for its OWN next step -> the store (the op everyone ELSE depends on)
//  is delayed behind self-serving loads -> late visibility -> extra retry
//  rounds (r11's FETCH +123MB).
//  Round-12 (k3) = r11 + ONE line: s_waitcnt vmcnt(0) right after the h-store,
//  before next step's xq prefetch + poll. Per-wave drain (consumer of wave
//  wv's slice only needs wave wv's store) — cheaper than r5's block barrier.
//  Everything else identical to r11 (passed, absmax 0):
//   - 64 blocks/dir x 8 cells; r5-verbatim batched poll (atomic loads x32,
//     ONE __all gate, s_sleep).
//   - swapped-operand MFMA, cell-pair row perm: lane owns all 4 gates of
//     cells 2q,2q+1 -> zero cross-lane epilogue, no LDS, no barrier.
//   - one aligned dword store per lane, 256B contiguous per wave.
//  r5: sentinel protocol (0xFFFF bf16 unreachable for h in (-1,1)).
//  r4: frag-order H layout; k4 consumes unchanged.
// ---------------------------------------------------------------------------

typedef short short8  __attribute__((ext_vector_type(8)));
typedef short short4v __attribute__((ext_vector_type(4)));
typedef float floatx4 __attribute__((ext_vector_type(4)));

#define OFF_XQ    0ULL               // [2*64][512] blocks of 2048 bf16  268,435,456 B
#define OFF_H     268435456ULL       // [2][512] frag-order blocks 64KB   67,108,864 B
#define OFF_EMB   335544320ULL       // [32768][512] bf16                 33,554,432 B
#define OFF_WIH   369098752ULL       // [2][2048][512] bf16                4,194,304 B
#define OFF_FCW   373293056ULL       // [48][1024] bf16                       98,304 B
#define OFF_BIAS  373391360ULL       // [2][2048] f32                         16,384 B
#define OFF_EM    373538816ULL       // [32768][48] f32                    6,291,456 B
#define OFF_NUM   379830272ULL       // [64] f32
#define OFF_LOGZ  379830528ULL       // [64] f32
#define WS_NEED   379830784ULL

__device__ __forceinline__ unsigned short f2bf(float f) {
  __hip_bfloat16 h = __float2bfloat16(f);
  unsigned short u; __builtin_memcpy(&u, &h, 2); return u;
}
__device__ __forceinline__ float bf2f(unsigned short u) {
  __hip_bfloat16 h; __builtin_memcpy(&h, &u, 2); return __bfloat162float(h);
}
__device__ __forceinline__ float sigm(float x) { return 1.0f / (1.0f + __expf(-x)); }
__device__ __forceinline__ float tanh_f(float x) {
  x = fmaxf(fminf(x, 15.0f), -15.0f);
  float e = __expf(2.0f * x);
  return (e - 1.0f) / (e + 1.0f);
}
// bijective time->block scramble (keeps H-slot addresses spread)
__device__ __forceinline__ int permt(int t) { return (t * 167) & 511; }

// ---------------- k_init: fill Hall with sentinel 0xFFFFFFFF ----------------
__global__ void k_init(uint4* __restrict__ H) {
  size_t i = (size_t)blockIdx.x * 256 + threadIdx.x;   // 16384*256 uint4 = 64 MB
  H[i] = (uint4){0xFFFFFFFFu, 0xFFFFFFFFu, 0xFFFFFFFFu, 0xFFFFFFFFu};
}

// ---------------- k0: conversions ----------------
__global__ void k0_conv(const float* __restrict__ wf, const float* __restrict__ wb,
                        const float* __restrict__ fcw,
                        const float* __restrict__ bihf, const float* __restrict__ bhhf,
                        const float* __restrict__ bihb, const float* __restrict__ bhhb,
                        unsigned short* __restrict__ wih_bf,
                        unsigned short* __restrict__ fcw_bf,
                        float* __restrict__ bias) {
  int i = blockIdx.x * 256 + threadIdx.x;
  if (i < 1048576) { wih_bf[i] = f2bf(wf[i]); return; }
  int j = i - 1048576;
  if (j < 1048576) { wih_bf[1048576 + j] = f2bf(wb[j]); return; }
  j -= 1048576;
  if (j < 49152) { fcw_bf[j] = f2bf(fcw[j]); return; }
  j -= 49152;
  if (j < 2048) { bias[j] = bihf[j] + bhhf[j]; return; }
  j -= 2048;
  if (j < 2048) { bias[2048 + j] = bihb[j] + bhhb[j]; return; }
}

// ---------------- k1: embedding gather -> bf16 ----------------
__global__ void k1_embed(const float* __restrict__ tab, const int* __restrict__ x,
                         unsigned short* __restrict__ emb_bf) {
  int tid = threadIdx.x;
#pragma unroll
  for (int r = 0; r < 4; ++r) {
    int m = blockIdx.x * 4 + r;          // m = t*64 + b
    int b = m & 63, t = m >> 6;
    int tok = x[b * 512 + t];
    const float2* src = (const float2*)(tab + (size_t)tok * 512);
    float2 v = src[tid];
    unsigned int pk = (unsigned int)f2bf(v.x) | ((unsigned int)f2bf(v.y) << 16);
    ((unsigned int*)(emb_bf + (size_t)m * 512))[tid] = pk;
  }
}

// ---------------- k2: input-projection GEMM -> xq layout ----------------
// xq block index (d*64+g)*512 + t, 2048 bf16 per block, inner: gate*512 + b*8 + ce
__global__ __launch_bounds__(256) void k2_xproj(
    const unsigned short* __restrict__ emb_bf, const unsigned short* __restrict__ wih_bf,
    const float* __restrict__ bias, unsigned short* __restrict__ xq) {
  const int mt = blockIdx.x * 128;
  const int nt = blockIdx.y * 128;
  const int d  = blockIdx.z;
  const unsigned short* W = wih_bf + (size_t)d * 2048 * 512;
  __shared__ short Bs[32768];                     // 64 KB (also epilogue scratch)
  const int tid = threadIdx.x, l = tid & 63, wv = tid >> 6;
  const int mh = wv & 1, nh = wv >> 1;
  floatx4 acc[4][4];
#pragma unroll
  for (int a = 0; a < 4; ++a)
#pragma unroll
    for (int b = 0; b < 4; ++b) acc[a][b] = (floatx4){0.f, 0.f, 0.f, 0.f};
  const unsigned short* Abase = emb_bf + (size_t)(mt + mh * 64) * 512;

  for (int kc = 0; kc < 2; ++kc) {
    __syncthreads();
#pragma unroll
    for (int i = 0; i < 16; ++i) {                // stage 64 B-fragments
      int f = i * 4 + wv;
      int nb2 = f & 7, ks = f >> 3;
      int n = nt + nb2 * 16 + (l & 15);
      int k = kc * 256 + ks * 32 + (l >> 4) * 8;
      short8 v = *(const short8*)(W + (size_t)n * 512 + k);
      *(short8*)(Bs + (f * 64 + l) * 8) = v;
    }
    __syncthreads();
#pragma unroll
    for (int ks = 0; ks < 8; ++ks) {
      int k0 = kc * 256 + ks * 32 + (l >> 4) * 8;
      short8 a[4];
#pragma unroll
      for (int mf = 0; mf < 4; ++mf)
        a[mf] = *(const short8*)(Abase + (size_t)(mf * 16 + (l & 15)) * 512 + k0);
#pragma unroll
      for (int nf = 0; nf < 4; ++nf) {
        short8 bfr = *(const short8*)(Bs + ((ks * 8 + nh * 4 + nf) * 64 + l) * 8);
#pragma unroll
        for (int mf = 0; mf < 4; ++mf)
          acc[mf][nf] = __builtin_amdgcn_mfma_f32_16x16x32_bf16(a[mf], bfr, acc[mf][nf], 0, 0, 0);
      }
    }
  }
  // ---- epilogue: LDS transpose into xq block layout ----
  __syncthreads();
#pragma unroll
  for (int nf = 0; nf < 4; ++nf) {
    int nl = nh * 64 + nf * 16 + (l & 15);
    float bs = bias[d * 2048 + nt + nl];
#pragma unroll
    for (int mf = 0; mf < 4; ++mf)
#pragma unroll
      for (int r = 0; r < 4; ++r) {
        int ml = mh * 64 + mf * 16 + (l >> 4) * 4 + r;
        Bs[ml * 136 + nl] = (short)f2bf(acc[mf][nf][r] + bs);  // stride 136: 16B-aligned rows
      }
  }
  __syncthreads();
  const int chunk = tid >> 3, sub = tid & 7;      // 32 chunks x 8 threads
  const int g_l = chunk & 15, t_l = chunk >> 4;
  const int gate = nt >> 9, g0 = (nt & 511) >> 3;
  size_t base = (((size_t)(d * 64 + g0 + g_l) * 512) + (size_t)(blockIdx.x * 2 + t_l)) * 2048
                + (size_t)gate * 512 + (size_t)sub * 64;
#pragma unroll
  for (int i = 0; i < 8; ++i) {                   // b = sub*8+i, pos = b*8+ce
    short8 v = *(const short8*)(Bs + (t_l * 64 + sub * 8 + i) * 136 + g_l * 8);
    *(short8*)(xq + base + i * 8) = v;
  }
}

// ---------------- k3: persistent BiLSTM, lane-local gates + store drain ----------------
__global__ __launch_bounds__(256, 1) void k3_lstm(
    const float* __restrict__ whh_f, const float* __restrict__ whh_b,
    const unsigned short* __restrict__ xq, unsigned short* __restrict__ Hall) {
  const int wgid = blockIdx.x;
  const int d = wgid >> 6, g = wgid & 63;
  const int tid = threadIdx.x, l = tid & 63, wv = tid >> 6;
  const float* whh = d ? whh_b : whh_f;

  // W_hh as MFMA A-operand fragments with cell-pair row permutation:
  // frag row nl = cA*4 + gate; tile T=0 -> cell 2cA, T=1 -> cell 2cA+1.
  // Bf[ks*2+T]; lane's k = ks*32 + (l>>4)*8.
  short8 Bf[32];
#pragma unroll
  for (int ks = 0; ks < 16; ++ks) {
#pragma unroll
    for (int T = 0; T < 2; ++T) {
      int nl = l & 15;
      int cA = nl >> 2, gate = nl & 3;
      int row = gate * 512 + g * 8 + 2 * cA + T;
      int k0 = ks * 32 + (l >> 4) * 8;
      const float* src = whh + (size_t)row * 512 + k0;
      short8 v;
#pragma unroll
      for (int j = 0; j < 8; ++j) v[j] = (short)f2bf(src[j]);
      Bf[ks * 2 + T] = v;
    }
  }

  const int q  = l >> 4;            // lane quarter: owns cells 2q, 2q+1
  const int bl = l & 15;            // batch low bits
  const int m  = wv * 16 + bl;      // this lane's batch
  float cst[2] = {0.f, 0.f};

  const unsigned long long* Hb =
      (const unsigned long long*)((const unsigned int*)Hall + (size_t)d * 8388608);
  unsigned int* Hw = (unsigned int*)Hall + (size_t)d * 8388608;
  const unsigned short* xqd = xq + ((size_t)(d * 64 + g) * 512) * 2048;

  // producer dword slot within a (d,t) 16384-dword frag block:
  // dims k1=8g+2q (low short), k2=8g+2q+1 (high) of batch m ->
  // dw = wv*4096 + (g>>2)*256 + (g&3)*64 + bl*4 + q  (wave = 256B contiguous)
  const size_t st_dw = (size_t)wv * 4096 + (size_t)(g >> 2) * 256
                     + (size_t)(g & 3) * 64 + bl * 4 + q;

  for (int s = 0; s < 512; ++s) {
    const int t = d ? (511 - s) : s;

    // prefetch xq: one dword per gate = cells 2q,2q+1 of batch m
    const unsigned int* xb = (const unsigned int*)(xqd + (size_t)t * 2048);
    unsigned int xu[4];
#pragma unroll
    for (int gate = 0; gate < 4; ++gate) xu[gate] = xb[gate * 256 + m * 4 + q];

    floatx4 acc0  = (floatx4){0.f, 0.f, 0.f, 0.f};   // cell 2q,   gates i,f,g,o
    floatx4 acc1  = (floatx4){0.f, 0.f, 0.f, 0.f};   // cell 2q+1, gates i,f,g,o
    floatx4 acc0b = (floatx4){0.f, 0.f, 0.f, 0.f};
    floatx4 acc1b = (floatx4){0.f, 0.f, 0.f, 0.f};
    if (s > 0) {
      const int tp = d ? (t + 1) : (t - 1);
      // r5-verbatim batched poll: load full 16KB wave chunk, single __all gate.
      const unsigned long long* Hu = Hb + (size_t)permt(tp) * 8192 + (size_t)wv * 2048;
      unsigned long long u[32];
      for (;;) {
#pragma unroll
        for (int ks = 0; ks < 16; ++ks) {
          u[2 * ks]     = __hip_atomic_load(Hu + (size_t)ks * 128 + 2 * l,
                                            __ATOMIC_RELAXED, __HIP_MEMORY_SCOPE_AGENT);
          u[2 * ks + 1] = __hip_atomic_load(Hu + (size_t)ks * 128 + 2 * l + 1,
                                            __ATOMIC_RELAXED, __HIP_MEMORY_SCOPE_AGENT);
        }
        bool ok = true;
#pragma unroll
        for (int i = 0; i < 32; ++i) {
          ok &= ((unsigned int)u[i] != 0xFFFFFFFFu);
          ok &= ((unsigned int)(u[i] >> 32) != 0xFFFFFFFFu);
        }
        if (__all((int)ok)) break;
        __builtin_amdgcn_s_sleep(1);
      }
      // 4 independent 8-deep MFMA chains; swapped operands -> D[nl][batch]:
      // lane (q,bl) holds rows 4q..4q+3 = (cA=q, gates 0..3), col = batch bl.
#pragma unroll
      for (int ks = 0; ks < 8; ++ks) {
        short8 af0, af1;
        __builtin_memcpy(&af0, &u[2 * ks], 8);
        __builtin_memcpy((char*)&af0 + 8, &u[2 * ks + 1], 8);
        __builtin_memcpy(&af1, &u[2 * (ks + 8)], 8);
        __builtin_memcpy((char*)&af1 + 8, &u[2 * (ks + 8) + 1], 8);
        acc0  = __builtin_amdgcn_mfma_f32_16x16x32_bf16(Bf[ks * 2 + 0], af0, acc0, 0, 0, 0);
        acc1  = __builtin_amdgcn_mfma_f32_16x16x32_bf16(Bf[ks * 2 + 1], af0, acc1, 0, 0, 0);
        acc0b = __builtin_amdgcn_mfma_f32_16x16x32_bf16(Bf[(ks + 8) * 2 + 0], af1, acc0b, 0, 0, 0);
        acc1b = __builtin_amdgcn_mfma_f32_16x16x32_bf16(Bf[(ks + 8) * 2 + 1], af1, acc1b, 0, 0, 0);
      }
      acc0 += acc0b;
      acc1 += acc1b;
    }

    // ---- elementwise: all 4 gates of both cells live in THIS lane ----
    float h2[2];
#pragma unroll
    for (int T = 0; T < 2; ++T) {
      floatx4 a = T ? acc1 : acc0;
      float gi = a[0] + bf2f((unsigned short)(xu[0] >> (16 * T)));
      float gf = a[1] + bf2f((unsigned short)(xu[1] >> (16 * T)));
      float gg = a[2] + bf2f((unsigned short)(xu[2] >> (16 * T)));
      float go = a[3] + bf2f((unsigned short)(xu[3] >> (16 * T)));
      float c = sigm(gf) * cst[T] + sigm(gi) * tanh_f(gg);
      cst[T] = c;
      h2[T] = sigm(go) * tanh_f(c);
    }
    // one aligned dword per lane (cells 2q,2q+1 adjacent in frag layout);
    // wave = 256B contiguous run. Write-through agent store = the signal.
    unsigned int hp = (unsigned int)f2bf(h2[0]) | ((unsigned int)f2bf(h2[1]) << 16);
    __hip_atomic_store(&Hw[(size_t)permt(t) * 16384 + st_dw], hp,
                       __ATOMIC_RELAXED, __HIP_MEMORY_SCOPE_AGENT);
    // THE round-12 change: drain our own store into the fabric BEFORE issuing
    // next step's self-serving poll loads. The store is the op every consumer
    // depends on; without this it queues behind 32 poll loads (r9/r10/r11
    // regression mechanism; r5's __syncthreads did this implicitly).
    asm volatile("s_waitcnt vmcnt(0)" ::: "memory");
  }
}

// ---------------- k4: emissions GEMM (frag-order H) ----------------
__global__ __launch_bounds__(256) void k4_emis(
    const unsigned short* __restrict__ Hall, const unsigned short* __restrict__ fcw_bf,
    const float* __restrict__ fcb, float* __restrict__ em) {
  __shared__ short Fs[48 * 520];
  const int tid = threadIdx.x, l = tid & 63, wv = tid >> 6;
  const int t = blockIdx.x;                      // M-tile 64 = one timestep
  floatx4 acc[3];
  acc[0] = acc[1] = acc[2] = (floatx4){0.f, 0.f, 0.f, 0.f};
  for (int half = 0; half < 2; ++half) {
    __syncthreads();
#pragma unroll
    for (int i = 0; i < 24; ++i) {
      int e4 = (tid + i * 256) * 4;
      int n = e4 >> 9, k = e4 & 511;
      *(short4v*)(Fs + n * 520 + k) =
          *(const short4v*)(fcw_bf + (size_t)n * 1024 + half * 512 + k);
    }
    __syncthreads();
    const unsigned short* Hsrc = Hall + (size_t)half * 16777216 + (size_t)permt(t) * 32768
                                 + (size_t)wv * 8192 + l * 8;
#pragma unroll
    for (int ks = 0; ks < 16; ++ks) {
      short8 a = *(const short8*)(Hsrc + ks * 512);
#pragma unroll
      for (int nf = 0; nf < 3; ++nf) {
        short8 bfr = *(const short8*)(Fs + (nf * 16 + (l & 15)) * 520 + ks * 32 + (l >> 4) * 8);
        acc[nf] = __builtin_amdgcn_mfma_f32_16x16x32_bf16(a, bfr, acc[nf], 0, 0, 0);
      }
    }
  }
#pragma unroll
  for (int nf = 0; nf < 3; ++nf) {
    int n = nf * 16 + (l & 15);
    float bv = fcb[n];
#pragma unroll
    for (int r = 0; r < 4; ++r) {
      int m = wv * 16 + (l >> 4) * 4 + r;        // batch
      em[((size_t)t * 64 + m) * 48 + n] = acc[nf][r] + bv;
    }
  }
}

// ---------------- k5: CRF numerator ----------------
__global__ void k5_num(const float* __restrict__ em, const int* __restrict__ tags,
                       const float* __restrict__ start, const float* __restrict__ endt,
                       const float* __restrict__ trans, float* __restrict__ num) {
  const int b = blockIdx.x, tid = threadIdx.x;
  float s = 0.f;
  for (int t = 1 + tid; t < 512; t += 256) {
    int tg = tags[b * 512 + t], tp = tags[b * 512 + t - 1];
    s += em[(size_t)(t * 64 + b) * 48 + tg] + trans[tp * 48 + tg];
  }
  if (tid == 0) {
    int t0 = tags[b * 512];
    s += start[t0] + em[(size_t)b * 48 + t0] + endt[tags[b * 512 + 511]];
  }
  __shared__ float red[256];
  red[tid] = s;
  __syncthreads();
  for (int o = 128; o > 0; o >>= 1) {
    if (tid < o) red[tid] += red[tid + o];
    __syncthreads();
  }
  if (tid == 0) num[b] = red[0];
}

// ---------------- k6: CRF forward recursion (single wave, no barriers) ----------------
__global__ void k6_crf(const float* __restrict__ em, const float* __restrict__ trans,
                       const float* __restrict__ start, const float* __restrict__ endt,
                       float* __restrict__ logz) {
  const int b = blockIdx.x;
  const int j = threadIdx.x;   // 64 threads = ONE wave; lanes 48..63 inactive
  const bool act = j < 48;
  float Ecol[48];
#pragma unroll
  for (int i = 0; i < 48; ++i) Ecol[i] = act ? __expf(trans[i * 48 + j]) : 0.f;
  __shared__ float p[48];
  float alpha = act ? (start[j] + em[(size_t)b * 48 + j]) : -1e30f;
  for (int t = 1; t < 512; ++t) {
    float e_t = act ? em[(size_t)(t * 64 + b) * 48 + j] : 0.f;
    float m = alpha;
#pragma unroll
    for (int off = 32; off > 0; off >>= 1) m = fmaxf(m, __shfl_xor(m, off));
    if (act) p[j] = __expf(alpha - m);
    float ssum = 0.f;                       // single wave: LDS ops in-order, no barrier
#pragma unroll
    for (int i = 0; i < 48; ++i) ssum += p[i] * Ecol[i];
    alpha = act ? (m + __logf(ssum) + e_t) : -1e30f;
  }
  float v = act ? (alpha + endt[j]) : -1e30f;
  float m2 = v;
#pragma unroll
  for (int off = 32; off > 0; off >>= 1) m2 = fmaxf(m2, __shfl_xor(m2, off));
  float sz = act ? __expf(v - m2) : 0.f;
#pragma unroll
  for (int off = 32; off > 0; off >>= 1) sz += __shfl_xor(sz, off);
  if (j == 0) logz[b] = m2 + __logf(sz);
}

// ---------------- k7: final scalar ----------------
__global__ void k7_final(const float* __restrict__ num, const float* __restrict__ logz,
                         float* __restrict__ out) {
  int l = threadIdx.x;
  float v = num[l] - logz[l];
#pragma unroll
  for (int off = 32; off > 0; off >>= 1) v += __shfl_xor(v, off);
  if (l == 0) out[0] = -v * (1.0f / 64.0f);
}

// ---------------------------------------------------------------------------
extern "C" void kernel_launch(void* const* d_in, const int* in_sizes, int n_in,
                              void* d_out, int out_size, void* d_ws, size_t ws_size,
                              hipStream_t stream) {
  (void)in_sizes; (void)n_in; (void)out_size;
  if (ws_size < WS_NEED) return;

  const float* embedding = (const float*)d_in[0];
  const float* w_ih_f = (const float*)d_in[1];
  const float* w_hh_f = (const float*)d_in[2];
  const float* b_ih_f = (const float*)d_in[3];
  const float* b_hh_f = (const float*)d_in[4];
  const float* w_ih_b = (const float*)d_in[5];
  const float* w_hh_b = (const float*)d_in[6];
  const float* b_ih_b = (const float*)d_in[7];
  const float* b_hh_b = (const float*)d_in[8];
  const float* fc_w = (const float*)d_in[9];
  const float* fc_b = (const float*)d_in[10];
  const float* start_trans = (const float*)d_in[11];
  const float* end_trans = (const float*)d_in[12];
  const float* trans = (const float*)d_in[13];
  const int* x = (const int*)d_in[14];
  const int* tags = (const int*)d_in[15];

  char* ws = (char*)d_ws;
  unsigned short* xq     = (unsigned short*)(ws + OFF_XQ);
  unsigned short* Hall   = (unsigned short*)(ws + OFF_H);
  unsigned short* emb_bf = (unsigned short*)(ws + OFF_EMB);
  unsigned short* wih_bf = (unsigned short*)(ws + OFF_WIH);
  unsigned short* fcw_bf = (unsigned short*)(ws + OFF_FCW);
  float* bias  = (float*)(ws + OFF_BIAS);
  float* em    = (float*)(ws + OFF_EM);
  float* num   = (float*)(ws + OFF_NUM);
  float* logz  = (float*)(ws + OFF_LOGZ);

  k_init<<<16384, 256, 0, stream>>>((uint4*)Hall);
  k0_conv<<<8400, 256, 0, stream>>>(w_ih_f, w_ih_b, fc_w, b_ih_f, b_hh_f, b_ih_b, b_hh_b,
                                    wih_bf, fcw_bf, bias);
  k1_embed<<<8192, 256, 0, stream>>>(embedding, x, emb_bf);
  k2_xproj<<<dim3(256, 16, 2), 256, 0, stream>>>(emb_bf, wih_bf, bias, xq);
  k3_lstm<<<128, 256, 0, stream>>>(w_hh_f, w_hh_b, xq, Hall);
  k4_emis<<<512, 256, 0, stream>>>(Hall, fcw_bf, fc_b, em);
  k5_num<<<64, 256, 0, stream>>>(em, tags, start_trans, end_trans, trans, num);
  k6_crf<<<64, 64, 0, stream>>>(em, trans, start_trans, end_trans, logz);
  k7_final<<<1, 64, 0, stream>>>(num, logz, (float*)d_out);
}